// Round 2
// baseline (544.368 us; speedup 1.0000x reference)
//
#include <hip/hip_runtime.h>
#include <float.h>

// VQ: B=32, C=64, H=64, W=64, N_EMBED=512
#define C_DIM   64
#define K_CODES 512
#define HW_BITS 12            // HW = 4096
#define N_TOK   131072
#define WAVES   4
#define KPW     (K_CODES / WAVES)   // 128 codes per wave

// Prep: transpose embed [C][K] -> eT [K][C], and norms[k] = ||e_k||^2.
__global__ __launch_bounds__(256) void vq_prep(const float* __restrict__ embed,
                                               float* __restrict__ eT,
                                               float* __restrict__ norms) {
    int k = blockIdx.x * blockDim.x + threadIdx.x;
    if (k >= K_CODES) return;
    float s = 0.f;
    #pragma unroll
    for (int c = 0; c < C_DIM; ++c) {
        float v = embed[c * K_CODES + k];   // coalesced across k
        eT[k * C_DIM + c] = v;
        s = fmaf(v, v, s);
    }
    norms[k] = s;
}

// Block = 256 threads = 4 waves over the SAME 64 tokens; wave w scans codes
// [128w, 128w+128) at wave-uniform addresses (scalar-load path), then the
// per-wave winners are combined in LDS in ascending-chunk order (first-min
// tie-break preserved). Per-(token,k) dot arithmetic identical to round 1.
__global__ __launch_bounds__(256, 4) void vq_main(const float* __restrict__ x,
                                                  const float* __restrict__ eT,
                                                  const float* __restrict__ norms,
                                                  float* __restrict__ out_qwg,
                                                  float* __restrict__ out_q,
                                                  float* __restrict__ out_ind) {
    const int lane = threadIdx.x & 63;
    const int wv   = threadIdx.x >> 6;
    const int tok  = (blockIdx.x << 6) + lane;
    const int b    = tok >> HW_BITS;
    const int hw   = tok & ((1 << HW_BITS) - 1);

    const float* xb = x + ((size_t)b << 18) + hw;   // b*C*HW + hw

    float f[C_DIM];
    #pragma unroll
    for (int c = 0; c < C_DIM; ++c) f[c] = xb[(size_t)c << HW_BITS];  // coalesced

    const int    k0    = wv * KPW;
    const float* eBase = eT + ((size_t)k0 << 6);
    const float* nBase = norms + k0;

    float best  = FLT_MAX;
    int   bestk = k0;
    #pragma unroll 2
    for (int kk = 0; kk < KPW; ++kk) {
        const float* e = eBase + (kk << 6);   // wave-uniform -> s_load
        float d0 = 0.f, d1 = 0.f, d2 = 0.f, d3 = 0.f;
        #pragma unroll
        for (int c = 0; c < C_DIM; c += 4) {
            d0 = fmaf(f[c + 0], e[c + 0], d0);
            d1 = fmaf(f[c + 1], e[c + 1], d1);
            d2 = fmaf(f[c + 2], e[c + 2], d2);
            d3 = fmaf(f[c + 3], e[c + 3], d3);
        }
        float dot   = (d0 + d1) + (d2 + d3);
        float score = fmaf(-2.f, dot, nBase[kk]);   // same formula as round 1
        if (score < best) { best = score; bestk = k0 + kk; }  // strict < = first min
    }

    __shared__ float sS[WAVES][64];
    __shared__ int   sI[WAVES][64];
    sS[wv][lane] = best;
    sI[wv][lane] = bestk;
    __syncthreads();

    // every thread recomputes the global winner (deterministic, all agree)
    float gb = sS[0][lane];
    int   gk = sI[0][lane];
    #pragma unroll
    for (int w = 1; w < WAVES; ++w) {
        float s = sS[w][lane];
        int   i = sI[w][lane];
        if (s < gb) { gb = s; gk = i; }   // ascending chunk order, strict <
    }

    // epilogue: wave wv writes features [16*wv, 16*wv+16) for its lane's token
    const float4* eq4 = (const float4*)(eT + ((size_t)gk << 6)) + (wv << 2);
    float* o0 = out_qwg + ((size_t)b << 18) + hw;
    float* o1 = out_q   + ((size_t)b << 18) + hw;
    #pragma unroll
    for (int j = 0; j < 4; ++j) {
        float4 qv = eq4[j];
        const int cb = (wv << 4) + (j << 2);
        o0[(size_t)(cb + 0) << HW_BITS] = f[cb + 0] + (qv.x - f[cb + 0]);
        o0[(size_t)(cb + 1) << HW_BITS] = f[cb + 1] + (qv.y - f[cb + 1]);
        o0[(size_t)(cb + 2) << HW_BITS] = f[cb + 2] + (qv.z - f[cb + 2]);
        o0[(size_t)(cb + 3) << HW_BITS] = f[cb + 3] + (qv.w - f[cb + 3]);
        o1[(size_t)(cb + 0) << HW_BITS] = qv.x;
        o1[(size_t)(cb + 1) << HW_BITS] = qv.y;
        o1[(size_t)(cb + 2) << HW_BITS] = qv.z;
        o1[(size_t)(cb + 3) << HW_BITS] = qv.w;
    }
    if (wv == 0) out_ind[tok] = (float)gk;
}

extern "C" void kernel_launch(void* const* d_in, const int* in_sizes, int n_in,
                              void* d_out, int out_size, void* d_ws, size_t ws_size,
                              hipStream_t stream) {
    const float* x     = (const float*)d_in[0];
    const float* embed = (const float*)d_in[1];

    float* out     = (float*)d_out;
    float* out_qwg = out;                       // 8388608 f32
    float* out_q   = out + (size_t)8388608;     // 8388608 f32
    float* out_ind = out + (size_t)16777216;    // 131072 f32

    float* eT    = (float*)d_ws;                // 512*64 f32 = 128 KB
    float* norms = eT + K_CODES * C_DIM;        // 512 f32

    vq_prep<<<2, 256, 0, stream>>>(embed, eT, norms);
    vq_main<<<N_TOK / 64, 256, 0, stream>>>(x, eT, norms, out_qwg, out_q, out_ind);
}

// Round 3
// 159.379 us; speedup vs baseline: 3.4156x; 3.4156x over previous
//
#include <hip/hip_runtime.h>
#include <float.h>

// VQ: B=32, C=64, H=64, W=64, N_EMBED=512
#define C_DIM   64
#define K_CODES 512
#define HW_BITS 12            // HW = 4096
#define N_TOK   131072
#define WAVES   4
#define KPW     (K_CODES / WAVES)   // 128 codes per wave

// Prep: transpose embed [C][K] -> eT [K][C], and norms[k] = ||e_k||^2.
__global__ __launch_bounds__(256) void vq_prep(const float* __restrict__ embed,
                                               float* __restrict__ eT,
                                               float* __restrict__ norms) {
    int k = blockIdx.x * blockDim.x + threadIdx.x;
    if (k >= K_CODES) return;
    float s = 0.f;
    #pragma unroll
    for (int c = 0; c < C_DIM; ++c) {
        float v = embed[c * K_CODES + k];   // coalesced across k
        eT[k * C_DIM + c] = v;
        s = fmaf(v, v, s);
    }
    norms[k] = s;
}

// Block = 256 threads = 4 waves over the SAME 64 tokens; wave w scans codes
// [128w, 128w+128). wvu is readfirstlane'd -> provably wave-uniform -> the
// e-row loads stay on the scalar (s_load) path. Epilogue uses a wave-uniform
// branch so all f[] indices are compile-time constants (f stays in VGPRs).
__global__ __launch_bounds__(256, 4) void vq_main(const float* __restrict__ x,
                                                  const float* __restrict__ eT,
                                                  const float* __restrict__ norms,
                                                  float* __restrict__ out_qwg,
                                                  float* __restrict__ out_q,
                                                  float* __restrict__ out_ind) {
    const int lane = threadIdx.x & 63;
    const int wvu  = __builtin_amdgcn_readfirstlane((int)(threadIdx.x >> 6)); // uniform SGPR
    const int tok  = (blockIdx.x << 6) + lane;
    const int b    = tok >> HW_BITS;
    const int hw   = tok & ((1 << HW_BITS) - 1);

    const float* xb = x + ((size_t)b << 18) + hw;   // b*C*HW + hw

    float f[C_DIM];
    #pragma unroll
    for (int c = 0; c < C_DIM; ++c) f[c] = xb[(size_t)c << HW_BITS];  // coalesced

    const int    k0    = wvu * KPW;
    const float* eBase = eT + ((size_t)k0 << 6);    // wave-uniform base
    const float* nBase = norms + k0;

    float best  = FLT_MAX;
    int   bestk = k0;
    #pragma unroll 2
    for (int kk = 0; kk < KPW; ++kk) {
        const float* e = eBase + (kk << 6);   // uniform -> s_load path
        float d0 = 0.f, d1 = 0.f, d2 = 0.f, d3 = 0.f;
        #pragma unroll
        for (int c = 0; c < C_DIM; c += 4) {
            d0 = fmaf(f[c + 0], e[c + 0], d0);
            d1 = fmaf(f[c + 1], e[c + 1], d1);
            d2 = fmaf(f[c + 2], e[c + 2], d2);
            d3 = fmaf(f[c + 3], e[c + 3], d3);
        }
        float dot   = (d0 + d1) + (d2 + d3);
        float score = fmaf(-2.f, dot, nBase[kk]);   // same formula as round 1
        if (score < best) { best = score; bestk = k0 + kk; }  // strict < = first min
    }

    __shared__ float sS[WAVES][64];
    __shared__ int   sI[WAVES][64];
    sS[wvu][lane] = best;
    sI[wvu][lane] = bestk;
    __syncthreads();

    // every thread recomputes the global winner (deterministic, all agree)
    float gb = sS[0][lane];
    int   gk = sI[0][lane];
    #pragma unroll
    for (int w = 1; w < WAVES; ++w) {       // compile-time w
        float s = sS[w][lane];
        int   i = sI[w][lane];
        if (s < gb) { gb = s; gk = i; }     // ascending chunk order, strict <
    }

    // epilogue: wave wvu writes features [16*wvu, 16*wvu+16) for its lane's
    // token. CB0 is a literal in each branch -> f[] indices compile-time.
    const float4* eq4 = (const float4*)(eT + ((size_t)gk << 6)) + (wvu << 2);
    float* o0 = out_qwg + ((size_t)b << 18) + hw;
    float* o1 = out_q   + ((size_t)b << 18) + hw;

#define EPI_QUARTER(CB0)                                                          \
    {                                                                             \
        _Pragma("unroll")                                                         \
        for (int j = 0; j < 4; ++j) {                                             \
            float4 qv = eq4[j];                                                   \
            o0[(size_t)((CB0) + j*4 + 0) << HW_BITS] =                            \
                f[(CB0) + j*4 + 0] + (qv.x - f[(CB0) + j*4 + 0]);                 \
            o0[(size_t)((CB0) + j*4 + 1) << HW_BITS] =                            \
                f[(CB0) + j*4 + 1] + (qv.y - f[(CB0) + j*4 + 1]);                 \
            o0[(size_t)((CB0) + j*4 + 2) << HW_BITS] =                            \
                f[(CB0) + j*4 + 2] + (qv.z - f[(CB0) + j*4 + 2]);                 \
            o0[(size_t)((CB0) + j*4 + 3) << HW_BITS] =                            \
                f[(CB0) + j*4 + 3] + (qv.w - f[(CB0) + j*4 + 3]);                 \
            o1[(size_t)((CB0) + j*4 + 0) << HW_BITS] = qv.x;                      \
            o1[(size_t)((CB0) + j*4 + 1) << HW_BITS] = qv.y;                      \
            o1[(size_t)((CB0) + j*4 + 2) << HW_BITS] = qv.z;                      \
            o1[(size_t)((CB0) + j*4 + 3) << HW_BITS] = qv.w;                      \
        }                                                                         \
    }

    if (wvu == 0) {
        EPI_QUARTER(0)
        out_ind[tok] = (float)gk;
    } else if (wvu == 1) {
        EPI_QUARTER(16)
    } else if (wvu == 2) {
        EPI_QUARTER(32)
    } else {
        EPI_QUARTER(48)
    }
#undef EPI_QUARTER
}

extern "C" void kernel_launch(void* const* d_in, const int* in_sizes, int n_in,
                              void* d_out, int out_size, void* d_ws, size_t ws_size,
                              hipStream_t stream) {
    const float* x     = (const float*)d_in[0];
    const float* embed = (const float*)d_in[1];

    float* out     = (float*)d_out;
    float* out_qwg = out;                       // 8388608 f32
    float* out_q   = out + (size_t)8388608;     // 8388608 f32
    float* out_ind = out + (size_t)16777216;    // 131072 f32

    float* eT    = (float*)d_ws;                // 512*64 f32 = 128 KB
    float* norms = eT + K_CODES * C_DIM;        // 512 f32

    vq_prep<<<2, 256, 0, stream>>>(embed, eT, norms);
    vq_main<<<N_TOK / 64, 256, 0, stream>>>(x, eT, norms, out_qwg, out_q, out_ind);
}